// Round 1
// baseline (676.961 us; speedup 1.0000x reference)
//
#include <hip/hip_runtime.h>
#include <math.h>

#define BB 32
#define CC 256
#define NPIX 4096
#define SS 64
#define CD 128

#define WS_MEAN   0u
#define WS_RSTD   131072u
#define WS_WT     262144u
#define WS_BIAS   294912u
#define WS_WOUTT  295040u
#define WS_BCDT1  360576u
#define WS_AB     360576u
#define WS_BCDT2  17137792u
#define WS_H      33915008u
#define WS_H2T    34439296u

__global__ __launch_bounds__(256) void k_setup1(const float* __restrict__ w_bcdt,
        const float* __restrict__ ln_w, const float* __restrict__ ln_b,
        float* __restrict__ wT, float* __restrict__ bias) {
    int o = blockIdx.x;
    int c = threadIdx.x;
    float v = w_bcdt[o*256 + c];
    wT[c*128 + o] = v * ln_w[c];
    __shared__ float red[256];
    red[c] = v * ln_b[c];
    __syncthreads();
    for (int off = 128; off > 0; off >>= 1) {
        if (c < off) red[c] += red[c+off];
        __syncthreads();
    }
    if (c == 0) bias[o] = red[0];
}

__global__ __launch_bounds__(256) void k_setup2(const float* __restrict__ w_out,
        float* __restrict__ w_outT) {
    int o = blockIdx.x; int c = threadIdx.x;
    w_outT[c*256 + o] = w_out[o*256 + c];
}

__global__ __launch_bounds__(256) void k_stats(const float* __restrict__ x,
        float* __restrict__ mean, float* __restrict__ rstd) {
    int p = blockIdx.x*256 + threadIdx.x;
    int b = p >> 12, n = p & 4095;
    const float* xp = x + (size_t)b*CC*NPIX + n;
    float s = 0.f, sq = 0.f;
    #pragma unroll 4
    for (int c = 0; c < CC; ++c) {
        float v = xp[c*NPIX];
        s += v; sq += v*v;
    }
    float m = s * (1.0f/256.0f);
    float var = (sq - s*m) * (1.0f/255.0f);
    mean[p] = m;
    rstd[p] = 1.0f / sqrtf(var + 1e-5f);
}

__global__ __launch_bounds__(256) void k_proj(const float* __restrict__ x,
        const float* __restrict__ mean, const float* __restrict__ rstd,
        const float* __restrict__ wT, const float* __restrict__ bias,
        float* __restrict__ bcdt1) {
    int nc = blockIdx.x;
    int obase = blockIdx.y * 64;
    int b = blockIdx.z;
    int n = nc*256 + threadIdx.x;
    int p = b*NPIX + n;
    float m = mean[p], r = rstd[p];
    const float* xp = x + (size_t)b*CC*NPIX + n;
    float acc[64];
    #pragma unroll
    for (int o = 0; o < 64; ++o) acc[o] = 0.f;
    for (int c = 0; c < CC; ++c) {
        float xn = (xp[c*NPIX] - m) * r;
        const float* wrow = wT + c*128 + obase;
        #pragma unroll
        for (int o = 0; o < 64; ++o) acc[o] = fmaf(wrow[o], xn, acc[o]);
    }
    float* op = bcdt1 + ((size_t)b*CD + obase)*NPIX + n;
    #pragma unroll
    for (int o = 0; o < 64; ++o) op[o*NPIX] = acc[o] + bias[obase + o];
}

__global__ __launch_bounds__(256) void k_gconv(const float* __restrict__ bcdt1,
        const float* __restrict__ w_gw, float* __restrict__ bcdt2) {
    int hbase = blockIdx.x * 16;
    int o = blockIdx.y;
    int b = blockIdx.z;
    int g = o >> 2;
    __shared__ float lin[4*18*66];
    for (int i = threadIdx.x; i < 4*18*66; i += 256) lin[i] = 0.f;
    __syncthreads();
    const float* src = bcdt1 + ((size_t)b*CD + g*4)*NPIX;
    for (int idx = threadIdx.x; idx < 4*18*64; idx += 256) {
        int ch = idx / 1152;
        int rem = idx - ch*1152;
        int rr = rem >> 6;
        int col = rem & 63;
        int grow = hbase - 1 + rr;
        if (grow >= 0 && grow < 64)
            lin[ch*1188 + rr*66 + col + 1] = src[ch*NPIX + grow*64 + col];
    }
    float wreg[36];
    #pragma unroll
    for (int j = 0; j < 36; ++j) wreg[j] = w_gw[o*36 + j];
    __syncthreads();
    int col = threadIdx.x & 63;
    int rsub = threadIdx.x >> 6;
    float* dst = bcdt2 + ((size_t)b*CD + o)*NPIX;
    #pragma unroll
    for (int q = 0; q < 4; ++q) {
        int rr = rsub + 4*q;
        float a = 0.f;
        #pragma unroll
        for (int i = 0; i < 4; ++i)
            #pragma unroll
            for (int dh = 0; dh < 3; ++dh)
                #pragma unroll
                for (int dw = 0; dw < 3; ++dw)
                    a = fmaf(wreg[i*9 + dh*3 + dw],
                             lin[i*1188 + (rr+dh)*66 + col + dw], a);
        dst[(hbase+rr)*64 + col] = a;
    }
}

__global__ __launch_bounds__(256) void k_softmax(const float* __restrict__ bcdt2,
        float* __restrict__ AB) {
    int s = blockIdx.x, b = blockIdx.y;
    const float4* dt = (const float4*)(bcdt2 + ((size_t)b*CD + 64 + s)*NPIX);
    const float4* bc = (const float4*)(bcdt2 + ((size_t)b*CD + s)*NPIX);
    float4* ab = (float4*)(AB + ((size_t)b*SS + s)*NPIX);
    int t = threadIdx.x;
    float4 v[4];
    float mx = -1e30f;
    #pragma unroll
    for (int k = 0; k < 4; ++k) {
        v[k] = dt[k*256 + t];
        mx = fmaxf(mx, fmaxf(fmaxf(v[k].x, v[k].y), fmaxf(v[k].z, v[k].w)));
    }
    #pragma unroll
    for (int off = 32; off > 0; off >>= 1) mx = fmaxf(mx, __shfl_down(mx, off, 64));
    __shared__ float buf[8];
    int w = t >> 6;
    if ((t & 63) == 0) buf[w] = mx;
    __syncthreads();
    mx = fmaxf(fmaxf(buf[0], buf[1]), fmaxf(buf[2], buf[3]));
    float sum = 0.f;
    #pragma unroll
    for (int k = 0; k < 4; ++k) {
        v[k].x = __expf(v[k].x - mx); v[k].y = __expf(v[k].y - mx);
        v[k].z = __expf(v[k].z - mx); v[k].w = __expf(v[k].w - mx);
        sum += v[k].x + v[k].y + v[k].z + v[k].w;
    }
    #pragma unroll
    for (int off = 32; off > 0; off >>= 1) sum += __shfl_down(sum, off, 64);
    if ((t & 63) == 0) buf[4+w] = sum;
    __syncthreads();
    float inv = 1.0f / (buf[4] + buf[5] + buf[6] + buf[7]);
    #pragma unroll
    for (int k = 0; k < 4; ++k) {
        float4 bcv = bc[k*256 + t];
        float4 o;
        o.x = v[k].x * inv * bcv.x;
        o.y = v[k].y * inv * bcv.y;
        o.z = v[k].z * inv * bcv.z;
        o.w = v[k].w * inv * bcv.w;
        ab[k*256 + t] = o;
    }
}

__global__ __launch_bounds__(256) void k_h(const float* __restrict__ x,
        const float* __restrict__ AB, float* __restrict__ h) {
    int cbase = blockIdx.x * 16;
    int b = blockIdx.y;
    __shared__ float sX[16*132];
    __shared__ float sA[64*132];
    int t = threadIdx.x;
    int cg = t & 3, sg = (t >> 2) & 15, nsub = t >> 6;
    float acc[4][4];
    #pragma unroll
    for (int j = 0; j < 4; ++j)
        #pragma unroll
        for (int k = 0; k < 4; ++k) acc[j][k] = 0.f;
    const float* xb  = x  + ((size_t)b*CC + cbase)*NPIX;
    const float* abb = AB + (size_t)b*SS*NPIX;
    for (int ch = 0; ch < 32; ++ch) {
        int nbase = ch*128;
        __syncthreads();
        #pragma unroll
        for (int k = 0; k < 2; ++k) {
            int idx = k*256 + t;
            int row = idx >> 5, c4 = idx & 31;
            float4 v = *(const float4*)(xb + (size_t)row*NPIX + nbase + c4*4);
            *(float4*)(sX + row*132 + c4*4) = v;
        }
        #pragma unroll
        for (int k = 0; k < 8; ++k) {
            int idx = k*256 + t;
            int row = idx >> 5, c4 = idx & 31;
            float4 v = *(const float4*)(abb + (size_t)row*NPIX + nbase + c4*4);
            *(float4*)(sA + row*132 + c4*4) = v;
        }
        __syncthreads();
        #pragma unroll
        for (int i = 0; i < 8; ++i) {
            int nq = nsub*8 + i;
            float4 xv[4], av[4];
            #pragma unroll
            for (int j = 0; j < 4; ++j) xv[j] = *(const float4*)(sX + (cg + 4*j)*132 + nq*4);
            #pragma unroll
            for (int k = 0; k < 4; ++k) av[k] = *(const float4*)(sA + (sg + 16*k)*132 + nq*4);
            #pragma unroll
            for (int j = 0; j < 4; ++j)
                #pragma unroll
                for (int k = 0; k < 4; ++k) {
                    acc[j][k] = fmaf(xv[j].x, av[k].x, acc[j][k]);
                    acc[j][k] = fmaf(xv[j].y, av[k].y, acc[j][k]);
                    acc[j][k] = fmaf(xv[j].z, av[k].z, acc[j][k]);
                    acc[j][k] = fmaf(xv[j].w, av[k].w, acc[j][k]);
                }
        }
    }
    __syncthreads();
    float* red = sA;
    #pragma unroll
    for (int j = 0; j < 4; ++j)
        #pragma unroll
        for (int k = 0; k < 4; ++k) red[t*16 + j*4 + k] = acc[j][k];
    __syncthreads();
    if (t < 64) {
        #pragma unroll
        for (int j = 0; j < 4; ++j)
            #pragma unroll
            for (int k = 0; k < 4; ++k) {
                int m = j*4 + k;
                float v = red[t*16+m] + red[(t+64)*16+m]
                        + red[(t+128)*16+m] + red[(t+192)*16+m];
                h[((size_t)b*CC + cbase + cg + 4*j)*SS + sg + 16*k] = v;
            }
    }
}

__global__ __launch_bounds__(256) void k_h2(const float* __restrict__ h,
        const float* __restrict__ w_outT, float* __restrict__ h2t) {
    int sbase = blockIdx.x * 8;
    int b = blockIdx.y;
    __shared__ float hl[256*8];
    int t = threadIdx.x;
    #pragma unroll
    for (int k = 0; k < 8; ++k) {
        int idx = k*256 + t;
        int c = idx >> 3, sc = idx & 7;
        hl[idx] = h[((size_t)b*CC + c)*SS + sbase + sc];
    }
    __syncthreads();
    float4 a0 = {0,0,0,0}, a1 = {0,0,0,0};
    #pragma unroll 8
    for (int c = 0; c < 256; ++c) {
        float wv = w_outT[c*256 + t];
        float4 h0 = *(const float4*)(hl + c*8);
        float4 h1 = *(const float4*)(hl + c*8 + 4);
        a0.x = fmaf(wv, h0.x, a0.x); a0.y = fmaf(wv, h0.y, a0.y);
        a0.z = fmaf(wv, h0.z, a0.z); a0.w = fmaf(wv, h0.w, a0.w);
        a1.x = fmaf(wv, h1.x, a1.x); a1.y = fmaf(wv, h1.y, a1.y);
        a1.z = fmaf(wv, h1.z, a1.z); a1.w = fmaf(wv, h1.w, a1.w);
    }
    float* dst = h2t + ((size_t)b*SS + sbase)*CC + t;
    dst[0*CC] = a0.x; dst[1*CC] = a0.y; dst[2*CC] = a0.z; dst[3*CC] = a0.w;
    dst[4*CC] = a1.x; dst[5*CC] = a1.y; dst[6*CC] = a1.z; dst[7*CC] = a1.w;
}

__global__ __launch_bounds__(256) void k_out(const float* __restrict__ x,
        const float* __restrict__ bcdt2, const float* __restrict__ h2t,
        float* __restrict__ out) {
    int obase = blockIdx.x * 64;
    int nbase = blockIdx.y * 128;
    int b = blockIdx.z;
    __shared__ float sBC[64*128];
    __shared__ float sH2[64*64];
    int t = threadIdx.x;
    #pragma unroll
    for (int k = 0; k < 8; ++k) {
        int idx = k*256 + t;
        int row = idx >> 5, c4 = idx & 31;
        float4 v = *(const float4*)(bcdt2 + ((size_t)b*CD + row)*NPIX + nbase + c4*4);
        *(float4*)(sBC + row*128 + c4*4) = v;
    }
    #pragma unroll
    for (int k = 0; k < 4; ++k) {
        int idx = k*256 + t;
        int row = idx >> 4, c4 = idx & 15;
        float4 v = *(const float4*)(h2t + ((size_t)b*SS + row)*CC + obase + c4*4);
        *(float4*)(sH2 + row*64 + c4*4) = v;
    }
    __syncthreads();
    int nq = t & 31, og = t >> 5;
    #pragma unroll
    for (int ot = 0; ot < 2; ++ot) {
        int ocol = ot*32 + og*4;
        float4 a[4];
        #pragma unroll
        for (int oo = 0; oo < 4; ++oo) a[oo] = make_float4(0.f, 0.f, 0.f, 0.f);
        for (int s = 0; s < 64; ++s) {
            float4 bcv = *(const float4*)(sBC + s*128 + nq*4);
            float4 hv  = *(const float4*)(sH2 + s*64 + ocol);
            a[0].x = fmaf(hv.x, bcv.x, a[0].x); a[0].y = fmaf(hv.x, bcv.y, a[0].y);
            a[0].z = fmaf(hv.x, bcv.z, a[0].z); a[0].w = fmaf(hv.x, bcv.w, a[0].w);
            a[1].x = fmaf(hv.y, bcv.x, a[1].x); a[1].y = fmaf(hv.y, bcv.y, a[1].y);
            a[1].z = fmaf(hv.y, bcv.z, a[1].z); a[1].w = fmaf(hv.y, bcv.w, a[1].w);
            a[2].x = fmaf(hv.z, bcv.x, a[2].x); a[2].y = fmaf(hv.z, bcv.y, a[2].y);
            a[2].z = fmaf(hv.z, bcv.z, a[2].z); a[2].w = fmaf(hv.z, bcv.w, a[2].w);
            a[3].x = fmaf(hv.w, bcv.x, a[3].x); a[3].y = fmaf(hv.w, bcv.y, a[3].y);
            a[3].z = fmaf(hv.w, bcv.z, a[3].z); a[3].w = fmaf(hv.w, bcv.w, a[3].w);
        }
        #pragma unroll
        for (int oo = 0; oo < 4; ++oo) {
            int o = obase + ocol + oo;
            const float4 xv = *(const float4*)(x + ((size_t)b*CC + o)*NPIX + nbase + nq*4);
            float4 r;
            r.x = a[oo].x + xv.x; r.y = a[oo].y + xv.y;
            r.z = a[oo].z + xv.z; r.w = a[oo].w + xv.w;
            *(float4*)(out + ((size_t)b*CC + o)*NPIX + nbase + nq*4) = r;
        }
    }
}

extern "C" void kernel_launch(void* const* d_in, const int* in_sizes, int n_in,
                              void* d_out, int out_size, void* d_ws, size_t ws_size,
                              hipStream_t stream) {
    const float* x      = (const float*)d_in[0];
    const float* ln_w   = (const float*)d_in[1];
    const float* ln_b   = (const float*)d_in[2];
    const float* w_bcdt = (const float*)d_in[3];
    const float* w_gw   = (const float*)d_in[4];
    const float* w_out  = (const float*)d_in[5];
    // d_in[6] = A: constant along softmax axis, cancels exactly.
    float* ws  = (float*)d_ws;
    float* out = (float*)d_out;

    float* mean   = ws + WS_MEAN;
    float* rstd   = ws + WS_RSTD;
    float* wT     = ws + WS_WT;
    float* bias   = ws + WS_BIAS;
    float* w_outT = ws + WS_WOUTT;
    float* bcdt1  = ws + WS_BCDT1;
    float* bcdt2  = ws + WS_BCDT2;
    float* AB     = ws + WS_AB;
    float* h      = ws + WS_H;
    float* h2t    = ws + WS_H2T;

    k_setup1<<<128, 256, 0, stream>>>(w_bcdt, ln_w, ln_b, wT, bias);
    k_setup2<<<256, 256, 0, stream>>>(w_out, w_outT);
    k_stats<<<512, 256, 0, stream>>>(x, mean, rstd);
    k_proj<<<dim3(16, 2, 32), 256, 0, stream>>>(x, mean, rstd, wT, bias, bcdt1);
    k_gconv<<<dim3(4, 128, 32), 256, 0, stream>>>(bcdt1, w_gw, bcdt2);
    k_softmax<<<dim3(64, 32), 256, 0, stream>>>(bcdt2, AB);
    k_h<<<dim3(16, 32), 256, 0, stream>>>(x, AB, h);
    k_h2<<<dim3(8, 32), 256, 0, stream>>>(h, w_outT, h2t);
    k_out<<<dim3(4, 32, 32), 256, 0, stream>>>(x, bcdt2, h2t, out);
}

// Round 2
// 673.471 us; speedup vs baseline: 1.0052x; 1.0052x over previous
//
#include <hip/hip_runtime.h>
#include <math.h>

#define BB 32
#define CC 256
#define NPIX 4096
#define SS 64
#define CD 128

// workspace layout (float offsets)
#define WS_WT     262144u          // 256*128  (w_bcdt^T * ln_w)
#define WS_BIAS   294912u          // 128
#define WS_WOUTT  295040u          // 256*256
#define WS_BCDT1  360576u          // 32*128*4096 (16777216 floats)
#define WS_AB     360576u          // aliases bcdt1[0 .. 8388608)
#define WS_HPART  8749184u         // aliases bcdt1[8388608 ..): 4*32*256*64 floats
#define WS_BCDT2  17137792u        // 32*128*4096
#define WS_H2T    34439296u        // 32*64*256

__global__ __launch_bounds__(256) void k_setup1(const float* __restrict__ w_bcdt,
        const float* __restrict__ ln_w, const float* __restrict__ ln_b,
        float* __restrict__ wT, float* __restrict__ bias) {
    int o = blockIdx.x;
    int c = threadIdx.x;
    float v = w_bcdt[o*256 + c];
    wT[c*128 + o] = v * ln_w[c];
    __shared__ float red[256];
    red[c] = v * ln_b[c];
    __syncthreads();
    for (int off = 128; off > 0; off >>= 1) {
        if (c < off) red[c] += red[c+off];
        __syncthreads();
    }
    if (c == 0) bias[o] = red[0];
}

__global__ __launch_bounds__(256) void k_setup2(const float* __restrict__ w_out,
        float* __restrict__ w_outT) {
    int o = blockIdx.x; int c = threadIdx.x;
    w_outT[c*256 + o] = w_out[o*256 + c];
}

// fused LN-stats + normalize + 1x1 proj.
// block = 512 threads: half 0 -> outputs [0,64), half 1 -> [64,128).
// x tile (16c x 256n) staged in LDS once, shared by both halves.
__global__ __launch_bounds__(512) void k_proj(const float* __restrict__ x,
        const float* __restrict__ wT, const float* __restrict__ bias,
        float* __restrict__ bcdt1) {
    int b = blockIdx.y;
    int nbase = blockIdx.x * 256;
    int tid = threadIdx.x;
    int half = tid >> 8;
    int tt = tid & 255;
    // wave-uniform (waves don't straddle the 256 boundary); force to SGPR so
    // weight loads stay scalar.
    int obase = __builtin_amdgcn_readfirstlane(half * 64);
    int n = nbase + tt;
    const float* xp = x + (size_t)b*CC*NPIX + n;

    // pass 1: LN stats, each half sums 128 channels, combine via LDS
    __shared__ float sSum[2][256];
    __shared__ float sSq[2][256];
    float s = 0.f, sq = 0.f;
    int c0 = half * 128;
    #pragma unroll 8
    for (int c = c0; c < c0 + 128; ++c) {
        float v = xp[(size_t)c*NPIX];
        s += v; sq += v*v;
    }
    sSum[half][tt] = s; sSq[half][tt] = sq;
    __syncthreads();
    s  = sSum[0][tt] + sSum[1][tt];
    sq = sSq[0][tt]  + sSq[1][tt];
    float m = s * (1.0f/256.0f);
    float r = 1.0f / sqrtf((sq - s*m) * (1.0f/255.0f) + 1e-5f);

    // pass 2: staged GEMV, x tile via LDS (L2-hot from pass 1)
    float acc[64];
    #pragma unroll
    for (int o = 0; o < 64; ++o) acc[o] = 0.f;
    __shared__ float sX[16*256];
    const float* xbase = x + (size_t)b*CC*NPIX + nbase;
    for (int cc = 0; cc < 256; cc += 16) {
        __syncthreads();
        #pragma unroll
        for (int k = 0; k < 8; ++k) {
            int i = k*512 + tid;
            int c = i >> 8, nn = i & 255;
            sX[c*256 + nn] = xbase[(size_t)(cc + c)*NPIX + nn];
        }
        __syncthreads();
        #pragma unroll
        for (int c2 = 0; c2 < 16; ++c2) {
            float xn = (sX[c2*256 + tt] - m) * r;
            const float* wrow = wT + (cc + c2)*128 + obase;
            #pragma unroll
            for (int o = 0; o < 64; ++o) acc[o] = fmaf(wrow[o], xn, acc[o]);
        }
    }
    float* op = bcdt1 + ((size_t)b*CD + obase)*NPIX + n;
    #pragma unroll
    for (int o = 0; o < 64; ++o) op[(size_t)o*NPIX] = acc[o] + bias[obase + o];
}

__global__ __launch_bounds__(256) void k_gconv(const float* __restrict__ bcdt1,
        const float* __restrict__ w_gw, float* __restrict__ bcdt2) {
    int hbase = blockIdx.x * 16;
    int o = blockIdx.y;
    int b = blockIdx.z;
    int g = o >> 2;
    __shared__ float lin[4*18*66];
    for (int i = threadIdx.x; i < 4*18*66; i += 256) lin[i] = 0.f;
    __syncthreads();
    const float* src = bcdt1 + ((size_t)b*CD + g*4)*NPIX;
    for (int idx = threadIdx.x; idx < 4*18*64; idx += 256) {
        int ch = idx / 1152;
        int rem = idx - ch*1152;
        int rr = rem >> 6;
        int col = rem & 63;
        int grow = hbase - 1 + rr;
        if (grow >= 0 && grow < 64)
            lin[ch*1188 + rr*66 + col + 1] = src[ch*NPIX + grow*64 + col];
    }
    float wreg[36];
    #pragma unroll
    for (int j = 0; j < 36; ++j) wreg[j] = w_gw[o*36 + j];
    __syncthreads();
    int col = threadIdx.x & 63;
    int rsub = threadIdx.x >> 6;
    float* dst = bcdt2 + ((size_t)b*CD + o)*NPIX;
    #pragma unroll
    for (int q = 0; q < 4; ++q) {
        int rr = rsub + 4*q;
        float a = 0.f;
        #pragma unroll
        for (int i = 0; i < 4; ++i)
            #pragma unroll
            for (int dh = 0; dh < 3; ++dh)
                #pragma unroll
                for (int dw = 0; dw < 3; ++dw)
                    a = fmaf(wreg[i*9 + dh*3 + dw],
                             lin[i*1188 + (rr+dh)*66 + col + dw], a);
        dst[(hbase+rr)*64 + col] = a;
    }
}

__global__ __launch_bounds__(256) void k_softmax(const float* __restrict__ bcdt2,
        float* __restrict__ AB) {
    int s = blockIdx.x, b = blockIdx.y;
    const float4* dt = (const float4*)(bcdt2 + ((size_t)b*CD + 64 + s)*NPIX);
    const float4* bc = (const float4*)(bcdt2 + ((size_t)b*CD + s)*NPIX);
    float4* ab = (float4*)(AB + ((size_t)b*SS + s)*NPIX);
    int t = threadIdx.x;
    float4 v[4];
    float mx = -1e30f;
    #pragma unroll
    for (int k = 0; k < 4; ++k) {
        v[k] = dt[k*256 + t];
        mx = fmaxf(mx, fmaxf(fmaxf(v[k].x, v[k].y), fmaxf(v[k].z, v[k].w)));
    }
    #pragma unroll
    for (int off = 32; off > 0; off >>= 1) mx = fmaxf(mx, __shfl_down(mx, off, 64));
    __shared__ float buf[8];
    int w = t >> 6;
    if ((t & 63) == 0) buf[w] = mx;
    __syncthreads();
    mx = fmaxf(fmaxf(buf[0], buf[1]), fmaxf(buf[2], buf[3]));
    float sum = 0.f;
    #pragma unroll
    for (int k = 0; k < 4; ++k) {
        v[k].x = __expf(v[k].x - mx); v[k].y = __expf(v[k].y - mx);
        v[k].z = __expf(v[k].z - mx); v[k].w = __expf(v[k].w - mx);
        sum += v[k].x + v[k].y + v[k].z + v[k].w;
    }
    #pragma unroll
    for (int off = 32; off > 0; off >>= 1) sum += __shfl_down(sum, off, 64);
    if ((t & 63) == 0) buf[4+w] = sum;
    __syncthreads();
    float inv = 1.0f / (buf[4] + buf[5] + buf[6] + buf[7]);
    #pragma unroll
    for (int k = 0; k < 4; ++k) {
        float4 bcv = bc[k*256 + t];
        float4 o;
        o.x = v[k].x * inv * bcv.x;
        o.y = v[k].y * inv * bcv.y;
        o.z = v[k].z * inv * bcv.z;
        o.w = v[k].w * inv * bcv.w;
        ab[k*256 + t] = o;
    }
}

// h_part[np][b][c][s] = sum_{n in chunk np} x[b][c][n] * AB[b][s][n]
// N split 4-way for occupancy; k_h2 reduces the partials.
__global__ __launch_bounds__(256) void k_h(const float* __restrict__ x,
        const float* __restrict__ AB, float* __restrict__ h_part) {
    int cbase = blockIdx.x * 16;
    int np = blockIdx.y;
    int b = blockIdx.z;
    __shared__ float sX[16*132];
    __shared__ float sA[64*132];
    int t = threadIdx.x;
    int cg = t & 3, sg = (t >> 2) & 15, nsub = t >> 6;
    float acc[4][4];
    #pragma unroll
    for (int j = 0; j < 4; ++j)
        #pragma unroll
        for (int k = 0; k < 4; ++k) acc[j][k] = 0.f;
    const float* xb  = x  + ((size_t)b*CC + cbase)*NPIX;
    const float* abb = AB + (size_t)b*SS*NPIX;
    for (int ch = 0; ch < 8; ++ch) {
        int nbase = np*1024 + ch*128;
        __syncthreads();
        #pragma unroll
        for (int k = 0; k < 2; ++k) {
            int idx = k*256 + t;
            int row = idx >> 5, c4 = idx & 31;
            float4 v = *(const float4*)(xb + (size_t)row*NPIX + nbase + c4*4);
            *(float4*)(sX + row*132 + c4*4) = v;
        }
        #pragma unroll
        for (int k = 0; k < 8; ++k) {
            int idx = k*256 + t;
            int row = idx >> 5, c4 = idx & 31;
            float4 v = *(const float4*)(abb + (size_t)row*NPIX + nbase + c4*4);
            *(float4*)(sA + row*132 + c4*4) = v;
        }
        __syncthreads();
        #pragma unroll
        for (int i = 0; i < 8; ++i) {
            int nq = nsub*8 + i;
            float4 xv[4], av[4];
            #pragma unroll
            for (int j = 0; j < 4; ++j) xv[j] = *(const float4*)(sX + (cg + 4*j)*132 + nq*4);
            #pragma unroll
            for (int k = 0; k < 4; ++k) av[k] = *(const float4*)(sA + (sg + 16*k)*132 + nq*4);
            #pragma unroll
            for (int j = 0; j < 4; ++j)
                #pragma unroll
                for (int k = 0; k < 4; ++k) {
                    acc[j][k] = fmaf(xv[j].x, av[k].x, acc[j][k]);
                    acc[j][k] = fmaf(xv[j].y, av[k].y, acc[j][k]);
                    acc[j][k] = fmaf(xv[j].z, av[k].z, acc[j][k]);
                    acc[j][k] = fmaf(xv[j].w, av[k].w, acc[j][k]);
                }
        }
    }
    __syncthreads();
    float* red = sA;
    #pragma unroll
    for (int j = 0; j < 4; ++j)
        #pragma unroll
        for (int k = 0; k < 4; ++k) red[t*16 + j*4 + k] = acc[j][k];
    __syncthreads();
    if (t < 64) {
        float* dst = h_part + ((size_t)np*BB + b)*CC*SS;
        #pragma unroll
        for (int j = 0; j < 4; ++j)
            #pragma unroll
            for (int k = 0; k < 4; ++k) {
                int mi = j*4 + k;
                float v = red[t*16+mi] + red[(t+64)*16+mi]
                        + red[(t+128)*16+mi] + red[(t+192)*16+mi];
                dst[(size_t)(cbase + cg + 4*j)*SS + sg + 16*k] = v;
            }
    }
}

// h2t[b][s][o] = sum_c w_out[o][c] * (sum_np h_part[np][b][c][s])
__global__ __launch_bounds__(256) void k_h2(const float* __restrict__ h_part,
        const float* __restrict__ w_outT, float* __restrict__ h2t) {
    int sbase = blockIdx.x * 8;
    int b = blockIdx.y;
    __shared__ float hl[256*8];
    int t = threadIdx.x;
    #pragma unroll
    for (int k = 0; k < 8; ++k) {
        int idx = k*256 + t;
        int c = idx >> 3, sc = idx & 7;
        size_t base = (size_t)b*CC*SS + (size_t)c*SS + sbase + sc;
        float v = h_part[base]
                + h_part[base + (size_t)1*BB*CC*SS]
                + h_part[base + (size_t)2*BB*CC*SS]
                + h_part[base + (size_t)3*BB*CC*SS];
        hl[idx] = v;
    }
    __syncthreads();
    float4 a0 = {0,0,0,0}, a1 = {0,0,0,0};
    #pragma unroll 8
    for (int c = 0; c < 256; ++c) {
        float wv = w_outT[c*256 + t];
        float4 h0 = *(const float4*)(hl + c*8);
        float4 h1 = *(const float4*)(hl + c*8 + 4);
        a0.x = fmaf(wv, h0.x, a0.x); a0.y = fmaf(wv, h0.y, a0.y);
        a0.z = fmaf(wv, h0.z, a0.z); a0.w = fmaf(wv, h0.w, a0.w);
        a1.x = fmaf(wv, h1.x, a1.x); a1.y = fmaf(wv, h1.y, a1.y);
        a1.z = fmaf(wv, h1.z, a1.z); a1.w = fmaf(wv, h1.w, a1.w);
    }
    float* dst = h2t + ((size_t)b*SS + sbase)*CC + t;
    dst[0*CC] = a0.x; dst[1*CC] = a0.y; dst[2*CC] = a0.z; dst[3*CC] = a0.w;
    dst[4*CC] = a1.x; dst[5*CC] = a1.y; dst[6*CC] = a1.z; dst[7*CC] = a1.w;
}

__global__ __launch_bounds__(256) void k_out(const float* __restrict__ x,
        const float* __restrict__ bcdt2, const float* __restrict__ h2t,
        float* __restrict__ out) {
    int obase = blockIdx.x * 64;
    int nbase = blockIdx.y * 128;
    int b = blockIdx.z;
    __shared__ float sBC[64*128];
    __shared__ float sH2[64*64];
    int t = threadIdx.x;
    #pragma unroll
    for (int k = 0; k < 8; ++k) {
        int idx = k*256 + t;
        int row = idx >> 5, c4 = idx & 31;
        float4 v = *(const float4*)(bcdt2 + ((size_t)b*CD + row)*NPIX + nbase + c4*4);
        *(float4*)(sBC + row*128 + c4*4) = v;
    }
    #pragma unroll
    for (int k = 0; k < 4; ++k) {
        int idx = k*256 + t;
        int row = idx >> 4, c4 = idx & 15;
        float4 v = *(const float4*)(h2t + ((size_t)b*SS + row)*CC + obase + c4*4);
        *(float4*)(sH2 + row*64 + c4*4) = v;
    }
    __syncthreads();
    int nq = t & 31, og = t >> 5;
    #pragma unroll
    for (int ot = 0; ot < 2; ++ot) {
        int ocol = ot*32 + og*4;
        float4 a[4];
        #pragma unroll
        for (int oo = 0; oo < 4; ++oo) a[oo] = make_float4(0.f, 0.f, 0.f, 0.f);
        for (int s = 0; s < 64; ++s) {
            float4 bcv = *(const float4*)(sBC + s*128 + nq*4);
            float4 hv  = *(const float4*)(sH2 + s*64 + ocol);
            a[0].x = fmaf(hv.x, bcv.x, a[0].x); a[0].y = fmaf(hv.x, bcv.y, a[0].y);
            a[0].z = fmaf(hv.x, bcv.z, a[0].z); a[0].w = fmaf(hv.x, bcv.w, a[0].w);
            a[1].x = fmaf(hv.y, bcv.x, a[1].x); a[1].y = fmaf(hv.y, bcv.y, a[1].y);
            a[1].z = fmaf(hv.y, bcv.z, a[1].z); a[1].w = fmaf(hv.y, bcv.w, a[1].w);
            a[2].x = fmaf(hv.z, bcv.x, a[2].x); a[2].y = fmaf(hv.z, bcv.y, a[2].y);
            a[2].z = fmaf(hv.z, bcv.z, a[2].z); a[2].w = fmaf(hv.z, bcv.w, a[2].w);
            a[3].x = fmaf(hv.w, bcv.x, a[3].x); a[3].y = fmaf(hv.w, bcv.y, a[3].y);
            a[3].z = fmaf(hv.w, bcv.z, a[3].z); a[3].w = fmaf(hv.w, bcv.w, a[3].w);
        }
        #pragma unroll
        for (int oo = 0; oo < 4; ++oo) {
            int o = obase + ocol + oo;
            const float4 xv = *(const float4*)(x + ((size_t)b*CC + o)*NPIX + nbase + nq*4);
            float4 r;
            r.x = a[oo].x + xv.x; r.y = a[oo].y + xv.y;
            r.z = a[oo].z + xv.z; r.w = a[oo].w + xv.w;
            *(float4*)(out + ((size_t)b*CC + o)*NPIX + nbase + nq*4) = r;
        }
    }
}

extern "C" void kernel_launch(void* const* d_in, const int* in_sizes, int n_in,
                              void* d_out, int out_size, void* d_ws, size_t ws_size,
                              hipStream_t stream) {
    const float* x      = (const float*)d_in[0];
    const float* ln_w   = (const float*)d_in[1];
    const float* ln_b   = (const float*)d_in[2];
    const float* w_bcdt = (const float*)d_in[3];
    const float* w_gw   = (const float*)d_in[4];
    const float* w_out  = (const float*)d_in[5];
    // d_in[6] = A: constant along softmax axis, cancels exactly.
    float* ws  = (float*)d_ws;
    float* out = (float*)d_out;

    float* wT     = ws + WS_WT;
    float* bias   = ws + WS_BIAS;
    float* w_outT = ws + WS_WOUTT;
    float* bcdt1  = ws + WS_BCDT1;
    float* bcdt2  = ws + WS_BCDT2;
    float* AB     = ws + WS_AB;
    float* h_part = ws + WS_HPART;
    float* h2t    = ws + WS_H2T;

    k_setup1<<<128, 256, 0, stream>>>(w_bcdt, ln_w, ln_b, wT, bias);
    k_setup2<<<256, 256, 0, stream>>>(w_out, w_outT);
    k_proj<<<dim3(16, 32), 512, 0, stream>>>(x, wT, bias, bcdt1);
    k_gconv<<<dim3(4, 128, 32), 256, 0, stream>>>(bcdt1, w_gw, bcdt2);
    k_softmax<<<dim3(64, 32), 256, 0, stream>>>(bcdt2, AB);
    k_h<<<dim3(16, 4, 32), 256, 0, stream>>>(x, AB, h_part);
    k_h2<<<dim3(8, 32), 256, 0, stream>>>(h_part, w_outT, h2t);
    k_out<<<dim3(4, 32, 32), 256, 0, stream>>>(x, bcdt2, h2t, out);
}

// Round 3
// 467.181 us; speedup vs baseline: 1.4490x; 1.4416x over previous
//
#include <hip/hip_runtime.h>
#include <math.h>

#define BB 32
#define CC 256
#define NPIX 4096
#define SS 64
#define CD 128

typedef __attribute__((ext_vector_type(8))) short bf16x8;
typedef __attribute__((ext_vector_type(4))) float f32x4;
typedef __attribute__((ext_vector_type(8))) unsigned short us8;

// workspace layout (float-element offsets)
#define WS_W1     0u          // 128*256 bf16 = 16384 float slots
#define WS_S1     16384u      // 128
#define WS_BIAS   16512u      // 128
#define WS_WOUTT  16640u      // 256*256 fp32
#define WS_BCDT1  82176u      // 32*128*4096 fp32 (dead after gconv -> aliased below)
#define WS_AB     82176u      // 32*64*4096 bf16 = 4194304 slots
#define WS_BCT    4276480u    // 32*4096*64 bf16 = 4194304 slots
#define WS_HPART  8470784u    // 4*32*256*64 fp32 = 2097152
#define WS_H2OS   10567936u   // 32*256*64 bf16 = 262144 slots
#define WS_BCDT2  16859392u   // 32*128*4096 bf16 = 8388608 slots
// end = 25248000 floats = 101 MB

__device__ inline short f2bf(float f) {
    union { float f; unsigned u; } v; v.f = f;
    unsigned r = v.u + 0x7fffu + ((v.u >> 16) & 1u);   // RNE
    return (short)(r >> 16);
}
__device__ inline float bf2f(unsigned short h) {
    union { unsigned u; float f; } v; v.u = ((unsigned)h) << 16;
    return v.f;
}
__device__ inline bf16x8 cvt8(float4 a, float4 b) {
    bf16x8 r;
    r[0]=f2bf(a.x); r[1]=f2bf(a.y); r[2]=f2bf(a.z); r[3]=f2bf(a.w);
    r[4]=f2bf(b.x); r[5]=f2bf(b.y); r[6]=f2bf(b.z); r[7]=f2bf(b.w);
    return r;
}

// W1[o][c] = bf16(w_bcdt[o][c]*ln_w[c]); S1[o]=sum_c bf2f(W1); bias[o]=sum_c w*ln_b
__global__ __launch_bounds__(256) void k_setup1(const float* __restrict__ w_bcdt,
        const float* __restrict__ ln_w, const float* __restrict__ ln_b,
        unsigned short* __restrict__ W1, float* __restrict__ S1, float* __restrict__ bias) {
    int o = blockIdx.x, c = threadIdx.x;
    float w = w_bcdt[o*256 + c];
    short h = f2bf(w * ln_w[c]);
    W1[o*256 + c] = (unsigned short)h;
    __shared__ float red[256];
    red[c] = bf2f((unsigned short)h);
    __syncthreads();
    for (int off = 128; off > 0; off >>= 1) { if (c < off) red[c] += red[c+off]; __syncthreads(); }
    if (c == 0) S1[o] = red[0];
    __syncthreads();
    red[c] = w * ln_b[c];
    __syncthreads();
    for (int off = 128; off > 0; off >>= 1) { if (c < off) red[c] += red[c+off]; __syncthreads(); }
    if (c == 0) bias[o] = red[0];
}

__global__ __launch_bounds__(256) void k_setup2(const float* __restrict__ w_out,
        float* __restrict__ w_outT) {
    int o = blockIdx.x, c = threadIdx.x;
    w_outT[c*256 + o] = w_out[o*256 + c];
}

// Fused LN-stats + bf16 transpose + MFMA proj. Block: (b, 64-n tile), 256 thr.
// bcdt1[o][n] = r[n]*(G[o][n] - m[n]*S1[o]) + bias[o],  G = W1 . bf16(x)
__global__ __launch_bounds__(256) void k_proj(const float* __restrict__ x,
        const unsigned short* __restrict__ W1, const float* __restrict__ S1,
        const float* __restrict__ bias, float* __restrict__ bcdt1) {
    int nbase = blockIdx.x * 64;
    int b = blockIdx.y;
    int tt = threadIdx.x;
    int wid = tt >> 6;            // wave id (uniform)
    int l = tt & 63;
    int lane16 = l & 15, q = l >> 4;

    __shared__ __align__(16) unsigned short sT[64*264];   // xT[n][c], row pad 264
    __shared__ float sStat[8][64];
    __shared__ float sM[64], sR[64];

    // phase 1: read x (c-strided, n-coalesced), stats + bf16 transpose into LDS
    {
        int n_l = tt & 63;
        int cq = tt >> 6;
        const float* xb = x + (size_t)b*CC*NPIX + nbase + n_l;
        float s = 0.f, sq = 0.f;
        #pragma unroll 8
        for (int i = 0; i < 64; ++i) {
            int c = cq*64 + i;
            float v = xb[(size_t)c*NPIX];
            s += v; sq += v*v;
            sT[n_l*264 + c] = (unsigned short)f2bf(v);
        }
        sStat[cq][n_l] = s; sStat[4+cq][n_l] = sq;
    }
    __syncthreads();
    if (tt < 64) {
        float s  = sStat[0][tt]+sStat[1][tt]+sStat[2][tt]+sStat[3][tt];
        float sq = sStat[4][tt]+sStat[5][tt]+sStat[6][tt]+sStat[7][tt];
        float m = s * (1.0f/256.0f);
        sM[tt] = m;
        sR[tt] = 1.0f / sqrtf((sq - s*m) * (1.0f/255.0f) + 1e-5f);
    }
    __syncthreads();

    // phase 2: MFMA. wave handles o in [wid*32, wid*32+32) (2 m-tiles) x 4 n-tiles
    f32x4 acc[2][4];
    #pragma unroll
    for (int i = 0; i < 2; ++i)
        #pragma unroll
        for (int j = 0; j < 4; ++j) acc[i][j] = (f32x4){0.f,0.f,0.f,0.f};
    int ob = wid * 32;
    for (int kk = 0; kk < 8; ++kk) {
        int k0 = kk * 32;
        bf16x8 a0 = *(const bf16x8*)(W1 + (size_t)(ob + lane16)*256 + k0 + q*8);
        bf16x8 a1 = *(const bf16x8*)(W1 + (size_t)(ob + 16 + lane16)*256 + k0 + q*8);
        bf16x8 bf[4];
        #pragma unroll
        for (int nt = 0; nt < 4; ++nt)
            bf[nt] = *(const bf16x8*)(sT + (nt*16 + lane16)*264 + k0 + q*8);
        #pragma unroll
        for (int nt = 0; nt < 4; ++nt) {
            acc[0][nt] = __builtin_amdgcn_mfma_f32_16x16x32_bf16(a0, bf[nt], acc[0][nt], 0, 0, 0);
            acc[1][nt] = __builtin_amdgcn_mfma_f32_16x16x32_bf16(a1, bf[nt], acc[1][nt], 0, 0, 0);
        }
    }
    // epilogue
    #pragma unroll
    for (int i = 0; i < 2; ++i)
        #pragma unroll
        for (int nt = 0; nt < 4; ++nt) {
            int n_l = nt*16 + lane16;
            float m = sM[n_l], r = sR[n_l];
            #pragma unroll
            for (int rr = 0; rr < 4; ++rr) {
                int o = ob + i*16 + q*4 + rr;
                float g = acc[i][nt][rr];
                float val = r * (g - m * S1[o]) + bias[o];
                bcdt1[((size_t)b*CD + o)*NPIX + nbase + n_l] = val;
            }
        }
}

// grouped 3x3 conv fp32 -> bf16 out
__global__ __launch_bounds__(256) void k_gconv(const float* __restrict__ bcdt1,
        const float* __restrict__ w_gw, unsigned short* __restrict__ bcdt2) {
    int hbase = blockIdx.x * 16;
    int o = blockIdx.y;
    int b = blockIdx.z;
    int g = o >> 2;
    __shared__ float lin[4*18*66];
    for (int i = threadIdx.x; i < 4*18*66; i += 256) lin[i] = 0.f;
    __syncthreads();
    const float* src = bcdt1 + ((size_t)b*CD + g*4)*NPIX;
    for (int idx = threadIdx.x; idx < 4*18*64; idx += 256) {
        int ch = idx / 1152;
        int rem = idx - ch*1152;
        int rr = rem >> 6;
        int col = rem & 63;
        int grow = hbase - 1 + rr;
        if (grow >= 0 && grow < 64)
            lin[ch*1188 + rr*66 + col + 1] = src[ch*NPIX + grow*64 + col];
    }
    float wreg[36];
    #pragma unroll
    for (int j = 0; j < 36; ++j) wreg[j] = w_gw[o*36 + j];
    __syncthreads();
    int col = threadIdx.x & 63;
    int rsub = threadIdx.x >> 6;
    unsigned short* dst = bcdt2 + ((size_t)b*CD + o)*NPIX;
    #pragma unroll
    for (int qq = 0; qq < 4; ++qq) {
        int rr = rsub + 4*qq;
        float a = 0.f;
        #pragma unroll
        for (int i = 0; i < 4; ++i)
            #pragma unroll
            for (int dh = 0; dh < 3; ++dh)
                #pragma unroll
                for (int dw = 0; dw < 3; ++dw)
                    a = fmaf(wreg[i*9 + dh*3 + dw],
                             lin[i*1188 + (rr+dh)*66 + col + dw], a);
        dst[(hbase+rr)*64 + col] = (unsigned short)f2bf(a);
    }
}

// softmax over N per (b,s); AB = softmax(dt) * BC, bf16 in/out
__global__ __launch_bounds__(256) void k_softmax(const unsigned short* __restrict__ bcdt2,
        unsigned short* __restrict__ AB) {
    int s = blockIdx.x, b = blockIdx.y, t = threadIdx.x;
    const us8* dt = (const us8*)(bcdt2 + ((size_t)b*CD + 64 + s)*NPIX);
    const us8* bc = (const us8*)(bcdt2 + ((size_t)b*CD + s)*NPIX);
    us8* ab = (us8*)(AB + ((size_t)b*SS + s)*NPIX);
    float f[16];
    us8 d0 = dt[t], d1 = dt[256 + t];
    #pragma unroll
    for (int j = 0; j < 8; ++j) { f[j] = bf2f(d0[j]); f[8+j] = bf2f(d1[j]); }
    float mx = -1e30f;
    #pragma unroll
    for (int j = 0; j < 16; ++j) mx = fmaxf(mx, f[j]);
    #pragma unroll
    for (int off = 32; off > 0; off >>= 1) mx = fmaxf(mx, __shfl_down(mx, off, 64));
    __shared__ float buf[8];
    int w = t >> 6;
    if ((t & 63) == 0) buf[w] = mx;
    __syncthreads();
    mx = fmaxf(fmaxf(buf[0], buf[1]), fmaxf(buf[2], buf[3]));
    float sum = 0.f;
    #pragma unroll
    for (int j = 0; j < 16; ++j) { f[j] = __expf(f[j] - mx); sum += f[j]; }
    #pragma unroll
    for (int off = 32; off > 0; off >>= 1) sum += __shfl_down(sum, off, 64);
    if ((t & 63) == 0) buf[4+w] = sum;
    __syncthreads();
    float inv = 1.0f / (buf[4] + buf[5] + buf[6] + buf[7]);
    us8 b0 = bc[t], b1 = bc[256 + t];
    us8 o0, o1;
    #pragma unroll
    for (int j = 0; j < 8; ++j) {
        o0[j] = (unsigned short)f2bf(f[j]   * inv * bf2f(b0[j]));
        o1[j] = (unsigned short)f2bf(f[8+j] * inv * bf2f(b1[j]));
    }
    ab[t] = o0; ab[256 + t] = o1;
}

// BCt[b][n][s] = BC[b][s][n]  (bf16 transpose, LDS tile)
__global__ __launch_bounds__(256) void k_tbc(const unsigned short* __restrict__ bcdt2,
        unsigned short* __restrict__ BCt) {
    int nb = blockIdx.x * 64;
    int b = blockIdx.y;
    __shared__ unsigned short tile[64*65];
    int tt = threadIdx.x;
    #pragma unroll
    for (int k = 0; k < 16; ++k) {
        int idx = k*256 + tt;
        int s = idx >> 6, n = idx & 63;
        tile[s*65 + n] = bcdt2[((size_t)b*CD + s)*NPIX + nb + n];
    }
    __syncthreads();
    #pragma unroll
    for (int k = 0; k < 16; ++k) {
        int idx = k*256 + tt;
        int n = idx >> 6, s = idx & 63;
        BCt[((size_t)b*NPIX + nb + n)*SS + s] = tile[s*65 + n];
    }
}

// h_part[kc][b][c][s] = sum_{n in kc-chunk} x[b][c][n]*AB[b][s][n]  (MFMA)
// block: (ctile64, kc, b); 4 waves split the 1024-n chunk; LDS merge.
__global__ __launch_bounds__(256) void k_h(const float* __restrict__ x,
        const unsigned short* __restrict__ AB, float* __restrict__ h_part) {
    int cb = blockIdx.x * 64;
    int kc = blockIdx.y;
    int b = blockIdx.z;
    int tt = threadIdx.x;
    int wid = tt >> 6;
    int l = tt & 63;
    int lane16 = l & 15, q = l >> 4;
    __shared__ __align__(16) float tile[2][64][68];   // [s][c] layout

    f32x4 acc[4][4];
    #pragma unroll
    for (int i = 0; i < 4; ++i)
        #pragma unroll
        for (int j = 0; j < 4; ++j) acc[i][j] = (f32x4){0.f,0.f,0.f,0.f};

    for (int kk = 0; kk < 8; ++kk) {
        int n0 = kc*1024 + wid*256 + kk*32;
        bf16x8 afr[4];
        #pragma unroll
        for (int mt = 0; mt < 4; ++mt) {
            const float* ap = x + ((size_t)b*CC + cb + mt*16 + lane16)*NPIX + n0 + q*8;
            float4 u0 = *(const float4*)ap;
            float4 u1 = *(const float4*)(ap + 4);
            afr[mt] = cvt8(u0, u1);
        }
        bf16x8 bfr[4];
        #pragma unroll
        for (int nt = 0; nt < 4; ++nt)
            bfr[nt] = *(const bf16x8*)(AB + ((size_t)b*SS + nt*16 + lane16)*NPIX + n0 + q*8);
        #pragma unroll
        for (int mt = 0; mt < 4; ++mt)
            #pragma unroll
            for (int nt = 0; nt < 4; ++nt)
                acc[mt][nt] = __builtin_amdgcn_mfma_f32_16x16x32_bf16(afr[mt], bfr[nt], acc[mt][nt], 0, 0, 0);
    }

    // cross-wave merge: waves 2,3 -> LDS; 0,1 add; wave 1 -> LDS; 0 adds; 0 writes.
    if (wid >= 2) {
        #pragma unroll
        for (int mt = 0; mt < 4; ++mt)
            #pragma unroll
            for (int nt = 0; nt < 4; ++nt)
                *(float4*)&tile[wid-2][nt*16 + lane16][mt*16 + q*4] = *(float4*)&acc[mt][nt];
    }
    __syncthreads();
    if (wid < 2) {
        #pragma unroll
        for (int mt = 0; mt < 4; ++mt)
            #pragma unroll
            for (int nt = 0; nt < 4; ++nt) {
                float4 v = *(float4*)&tile[wid][nt*16 + lane16][mt*16 + q*4];
                acc[mt][nt][0] += v.x; acc[mt][nt][1] += v.y;
                acc[mt][nt][2] += v.z; acc[mt][nt][3] += v.w;
            }
    }
    __syncthreads();
    if (wid == 1) {
        #pragma unroll
        for (int mt = 0; mt < 4; ++mt)
            #pragma unroll
            for (int nt = 0; nt < 4; ++nt)
                *(float4*)&tile[0][nt*16 + lane16][mt*16 + q*4] = *(float4*)&acc[mt][nt];
    }
    __syncthreads();
    if (wid == 0) {
        float* dst = h_part + ((size_t)kc*BB + b)*CC*SS;
        #pragma unroll
        for (int mt = 0; mt < 4; ++mt)
            #pragma unroll
            for (int nt = 0; nt < 4; ++nt) {
                float4 v = *(float4*)&tile[0][nt*16 + lane16][mt*16 + q*4];
                int s = nt*16 + lane16;
                #pragma unroll
                for (int rr = 0; rr < 4; ++rr) {
                    int c = cb + mt*16 + q*4 + rr;
                    float pv = acc[mt][nt][rr] + ((const float*)&v)[rr];
                    dst[(size_t)c*SS + s] = pv;
                }
            }
    }
}

// h2os[b][o][s] = bf16( sum_c w_outT[c][o] * sum_kc h_part[kc][b][c][s] )
__global__ __launch_bounds__(256) void k_h2(const float* __restrict__ h_part,
        const float* __restrict__ w_outT, unsigned short* __restrict__ h2os) {
    int sbase = blockIdx.x * 8;
    int b = blockIdx.y;
    __shared__ float hl[256*8];
    int t = threadIdx.x;
    #pragma unroll
    for (int k = 0; k < 8; ++k) {
        int idx = k*256 + t;
        int c = idx >> 3, sc = idx & 7;
        size_t base = (size_t)b*CC*SS + (size_t)c*SS + sbase + sc;
        hl[idx] = h_part[base]
                + h_part[base + (size_t)1*BB*CC*SS]
                + h_part[base + (size_t)2*BB*CC*SS]
                + h_part[base + (size_t)3*BB*CC*SS];
    }
    __syncthreads();
    float4 a0 = {0,0,0,0}, a1 = {0,0,0,0};
    #pragma unroll 8
    for (int c = 0; c < 256; ++c) {
        float wv = w_outT[c*256 + t];
        float4 h0 = *(const float4*)(hl + c*8);
        float4 h1 = *(const float4*)(hl + c*8 + 4);
        a0.x = fmaf(wv, h0.x, a0.x); a0.y = fmaf(wv, h0.y, a0.y);
        a0.z = fmaf(wv, h0.z, a0.z); a0.w = fmaf(wv, h0.w, a0.w);
        a1.x = fmaf(wv, h1.x, a1.x); a1.y = fmaf(wv, h1.y, a1.y);
        a1.z = fmaf(wv, h1.z, a1.z); a1.w = fmaf(wv, h1.w, a1.w);
    }
    unsigned short* dst = h2os + ((size_t)b*CC + t)*SS + sbase;
    us8 pk;
    pk[0]=(unsigned short)f2bf(a0.x); pk[1]=(unsigned short)f2bf(a0.y);
    pk[2]=(unsigned short)f2bf(a0.z); pk[3]=(unsigned short)f2bf(a0.w);
    pk[4]=(unsigned short)f2bf(a1.x); pk[5]=(unsigned short)f2bf(a1.y);
    pk[6]=(unsigned short)f2bf(a1.z); pk[7]=(unsigned short)f2bf(a1.w);
    *(us8*)dst = pk;
}

// out[b][o][n] = sum_s h2os[b][o][s]*BCt[b][n][s] + x[b][o][n]  (MFMA, K=64)
__global__ __launch_bounds__(256) void k_out(const float* __restrict__ x,
        const unsigned short* __restrict__ h2os, const unsigned short* __restrict__ BCt,
        float* __restrict__ out) {
    int nb = blockIdx.x * 64;
    int b = blockIdx.y;
    int tt = threadIdx.x;
    int wid = tt >> 6;
    int l = tt & 63;
    int lane16 = l & 15, q = l >> 4;
    int ob = wid * 64;

    f32x4 acc[4][4];
    #pragma unroll
    for (int i = 0; i < 4; ++i)
        #pragma unroll
        for (int j = 0; j < 4; ++j) acc[i][j] = (f32x4){0.f,0.f,0.f,0.f};

    #pragma unroll
    for (int kk = 0; kk < 2; ++kk) {
        int s0 = kk*32;
        bf16x8 afr[4], bfr[4];
        #pragma unroll
        for (int mt = 0; mt < 4; ++mt)
            afr[mt] = *(const bf16x8*)(h2os + ((size_t)b*CC + ob + mt*16 + lane16)*SS + s0 + q*8);
        #pragma unroll
        for (int nt = 0; nt < 4; ++nt)
            bfr[nt] = *(const bf16x8*)(BCt + ((size_t)b*NPIX + nb + nt*16 + lane16)*SS + s0 + q*8);
        #pragma unroll
        for (int mt = 0; mt < 4; ++mt)
            #pragma unroll
            for (int nt = 0; nt < 4; ++nt)
                acc[mt][nt] = __builtin_amdgcn_mfma_f32_16x16x32_bf16(afr[mt], bfr[nt], acc[mt][nt], 0, 0, 0);
    }
    #pragma unroll
    for (int mt = 0; mt < 4; ++mt)
        #pragma unroll
        for (int nt = 0; nt < 4; ++nt) {
            int n = nb + nt*16 + lane16;
            #pragma unroll
            for (int rr = 0; rr < 4; ++rr) {
                int o = ob + mt*16 + q*4 + rr;
                size_t idx = ((size_t)b*CC + o)*NPIX + n;
                out[idx] = acc[mt][nt][rr] + x[idx];
            }
        }
}

extern "C" void kernel_launch(void* const* d_in, const int* in_sizes, int n_in,
                              void* d_out, int out_size, void* d_ws, size_t ws_size,
                              hipStream_t stream) {
    const float* x      = (const float*)d_in[0];
    const float* ln_w   = (const float*)d_in[1];
    const float* ln_b   = (const float*)d_in[2];
    const float* w_bcdt = (const float*)d_in[3];
    const float* w_gw   = (const float*)d_in[4];
    const float* w_out  = (const float*)d_in[5];
    // d_in[6] = A: constant along softmax axis, cancels exactly.
    float* ws  = (float*)d_ws;
    float* out = (float*)d_out;

    unsigned short* W1    = (unsigned short*)(ws + WS_W1);
    float* S1             = ws + WS_S1;
    float* bias           = ws + WS_BIAS;
    float* w_outT         = ws + WS_WOUTT;
    float* bcdt1          = ws + WS_BCDT1;
    unsigned short* bcdt2 = (unsigned short*)(ws + WS_BCDT2);
    unsigned short* AB    = (unsigned short*)(ws + WS_AB);
    unsigned short* BCt   = (unsigned short*)(ws + WS_BCT);
    float* h_part         = ws + WS_HPART;
    unsigned short* h2os  = (unsigned short*)(ws + WS_H2OS);

    k_setup1<<<128, 256, 0, stream>>>(w_bcdt, ln_w, ln_b, W1, S1, bias);
    k_setup2<<<256, 256, 0, stream>>>(w_out, w_outT);
    k_proj<<<dim3(64, 32), 256, 0, stream>>>(x, W1, S1, bias, bcdt1);
    k_gconv<<<dim3(4, 128, 32), 256, 0, stream>>>(bcdt1, w_gw, bcdt2);
    k_softmax<<<dim3(64, 32), 256, 0, stream>>>(bcdt2, AB);
    k_tbc<<<dim3(64, 32), 256, 0, stream>>>(bcdt2, BCt);
    k_h<<<dim3(4, 4, 32), 256, 0, stream>>>(x, AB, h_part);
    k_h2<<<dim3(8, 32), 256, 0, stream>>>(h_part, w_outT, h2os);
    k_out<<<dim3(64, 32), 256, 0, stream>>>(x, h2os, BCt, out);
}

// Round 4
// 429.070 us; speedup vs baseline: 1.5777x; 1.0888x over previous
//
#include <hip/hip_runtime.h>
#include <math.h>

#define BB 32
#define CC 256
#define NPIX 4096
#define SS 64
#define CD 128

typedef __attribute__((ext_vector_type(8))) short bf16x8;
typedef __attribute__((ext_vector_type(4))) float f32x4;
typedef __attribute__((ext_vector_type(8))) unsigned short us8;

// workspace layout (float-element offsets)
#define WS_W1     0u          // 128*256 bf16 = 16384 float slots
#define WS_S1     16384u      // 128
#define WS_BIAS   16512u      // 128
#define WS_WOUTT  16640u      // 256*256 fp32
#define WS_BCDT1  82176u      // 32*128*4096 fp32 (dead after gconv -> aliased below)
#define WS_AB     82176u      // 32*64*4096 bf16 = 4194304 slots
#define WS_BCT    4276480u    // 32*4096*64 bf16 = 4194304 slots
#define WS_HPART  8470784u    // 8*32*256*64 fp32 = 4194304
#define WS_H2OS   12665088u   // 32*256*64 bf16 = 131072 slots
#define WS_BCDT2  16859392u   // 32*128*4096 bf16 = 8388608 slots
// end = 25248000 floats = 101 MB

__device__ inline short f2bf(float f) {
    union { float f; unsigned u; } v; v.f = f;
    unsigned r = v.u + 0x7fffu + ((v.u >> 16) & 1u);   // RNE
    return (short)(r >> 16);
}
__device__ inline float bf2f(unsigned short h) {
    union { unsigned u; float f; } v; v.u = ((unsigned)h) << 16;
    return v.f;
}
__device__ inline bf16x8 cvt8(float4 a, float4 b) {
    bf16x8 r;
    r[0]=f2bf(a.x); r[1]=f2bf(a.y); r[2]=f2bf(a.z); r[3]=f2bf(a.w);
    r[4]=f2bf(b.x); r[5]=f2bf(b.y); r[6]=f2bf(b.z); r[7]=f2bf(b.w);
    return r;
}

// W1[o][c] = bf16(w_bcdt[o][c]*ln_w[c]); S1[o]=sum_c bf2f(W1); bias[o]=sum_c w*ln_b
__global__ __launch_bounds__(256) void k_setup1(const float* __restrict__ w_bcdt,
        const float* __restrict__ ln_w, const float* __restrict__ ln_b,
        unsigned short* __restrict__ W1, float* __restrict__ S1, float* __restrict__ bias) {
    int o = blockIdx.x, c = threadIdx.x;
    float w = w_bcdt[o*256 + c];
    short h = f2bf(w * ln_w[c]);
    W1[o*256 + c] = (unsigned short)h;
    __shared__ float red[256];
    red[c] = bf2f((unsigned short)h);
    __syncthreads();
    for (int off = 128; off > 0; off >>= 1) { if (c < off) red[c] += red[c+off]; __syncthreads(); }
    if (c == 0) S1[o] = red[0];
    __syncthreads();
    red[c] = w * ln_b[c];
    __syncthreads();
    for (int off = 128; off > 0; off >>= 1) { if (c < off) red[c] += red[c+off]; __syncthreads(); }
    if (c == 0) bias[o] = red[0];
}

__global__ __launch_bounds__(256) void k_setup2(const float* __restrict__ w_out,
        float* __restrict__ w_outT) {
    int o = blockIdx.x, c = threadIdx.x;
    w_outT[c*256 + o] = w_out[o*256 + c];
}

// Fused LN-stats + bf16 transpose + MFMA proj. Block: (b, 64-n tile), 256 thr.
// bcdt1[o][n] = r[n]*(G[o][n] - m[n]*S1[o]) + bias[o],  G = W1 . bf16(x)
__global__ __launch_bounds__(256) void k_proj(const float* __restrict__ x,
        const unsigned short* __restrict__ W1, const float* __restrict__ S1,
        const float* __restrict__ bias, float* __restrict__ bcdt1) {
    int nbase = blockIdx.x * 64;
    int b = blockIdx.y;
    int tt = threadIdx.x;
    int wid = tt >> 6;            // wave id (uniform)
    int l = tt & 63;
    int lane16 = l & 15, q = l >> 4;

    __shared__ __align__(16) unsigned short sT[64*264];   // xT[n][c], row pad 264
    __shared__ float sStat[8][64];
    __shared__ float sM[64], sR[64];

    // phase 1: read x (c-strided, n-coalesced), stats + bf16 transpose into LDS
    {
        int n_l = tt & 63;
        int cq = tt >> 6;
        const float* xb = x + (size_t)b*CC*NPIX + nbase + n_l;
        float s = 0.f, sq = 0.f;
        #pragma unroll 8
        for (int i = 0; i < 64; ++i) {
            int c = cq*64 + i;
            float v = xb[(size_t)c*NPIX];
            s += v; sq += v*v;
            sT[n_l*264 + c] = (unsigned short)f2bf(v);
        }
        sStat[cq][n_l] = s; sStat[4+cq][n_l] = sq;
    }
    __syncthreads();
    if (tt < 64) {
        float s  = sStat[0][tt]+sStat[1][tt]+sStat[2][tt]+sStat[3][tt];
        float sq = sStat[4][tt]+sStat[5][tt]+sStat[6][tt]+sStat[7][tt];
        float m = s * (1.0f/256.0f);
        sM[tt] = m;
        sR[tt] = 1.0f / sqrtf((sq - s*m) * (1.0f/255.0f) + 1e-5f);
    }
    __syncthreads();

    // phase 2: MFMA. wave handles o in [wid*32, wid*32+32) (2 m-tiles) x 4 n-tiles
    f32x4 acc[2][4];
    #pragma unroll
    for (int i = 0; i < 2; ++i)
        #pragma unroll
        for (int j = 0; j < 4; ++j) acc[i][j] = (f32x4){0.f,0.f,0.f,0.f};
    int ob = wid * 32;
    for (int kk = 0; kk < 8; ++kk) {
        int k0 = kk * 32;
        bf16x8 a0 = *(const bf16x8*)(W1 + (size_t)(ob + lane16)*256 + k0 + q*8);
        bf16x8 a1 = *(const bf16x8*)(W1 + (size_t)(ob + 16 + lane16)*256 + k0 + q*8);
        bf16x8 bf[4];
        #pragma unroll
        for (int nt = 0; nt < 4; ++nt)
            bf[nt] = *(const bf16x8*)(sT + (nt*16 + lane16)*264 + k0 + q*8);
        #pragma unroll
        for (int nt = 0; nt < 4; ++nt) {
            acc[0][nt] = __builtin_amdgcn_mfma_f32_16x16x32_bf16(a0, bf[nt], acc[0][nt], 0, 0, 0);
            acc[1][nt] = __builtin_amdgcn_mfma_f32_16x16x32_bf16(a1, bf[nt], acc[1][nt], 0, 0, 0);
        }
    }
    // epilogue
    #pragma unroll
    for (int i = 0; i < 2; ++i)
        #pragma unroll
        for (int nt = 0; nt < 4; ++nt) {
            int n_l = nt*16 + lane16;
            float m = sM[n_l], r = sR[n_l];
            #pragma unroll
            for (int rr = 0; rr < 4; ++rr) {
                int o = ob + i*16 + q*4 + rr;
                float g = acc[i][nt][rr];
                float val = r * (g - m * S1[o]) + bias[o];
                bcdt1[((size_t)b*CD + o)*NPIX + nbase + n_l] = val;
            }
        }
}

// grouped 3x3 conv: one block = one group (4 in-ch -> 4 out-ch), 16-row chunk.
// Register-held 6x3 window per input channel, reused across 4 out-ch x 4 rows.
__global__ __launch_bounds__(256) void k_gconv(const float* __restrict__ bcdt1,
        const float* __restrict__ w_gw, unsigned short* __restrict__ bcdt2) {
    int hbase = blockIdx.x * 16;
    int g = blockIdx.y;
    int b = blockIdx.z;
    __shared__ float lin[4][18][66];
    int tt = threadIdx.x;
    int col = tt & 63, ch = tt >> 6;

    // stage rows hbase-1 .. hbase+16 of 4 channels; index math is shifts only
    const float* src = bcdt1 + ((size_t)b*CD + g*4 + ch)*NPIX;
    #pragma unroll
    for (int k = 0; k < 18; ++k) {
        int grow = hbase - 1 + k;
        float v = (grow >= 0 && grow < 64) ? src[grow*64 + col] : 0.f;
        lin[ch][k][col + 1] = v;
    }
    if (col == 0 || col == 63) {
        int pc = (col == 0) ? 0 : 65;
        #pragma unroll
        for (int k = 0; k < 18; ++k) lin[ch][k][pc] = 0.f;
    }
    __syncthreads();

    int r0 = ch * 4;          // this thread's 4 output rows within the 16-chunk
    float acc[4][4];
    #pragma unroll
    for (int oc = 0; oc < 4; ++oc)
        #pragma unroll
        for (int r = 0; r < 4; ++r) acc[oc][r] = 0.f;

    #pragma unroll
    for (int ic = 0; ic < 4; ++ic) {
        float val[6][3];
        #pragma unroll
        for (int rr = 0; rr < 6; ++rr)
            #pragma unroll
            for (int dw = 0; dw < 3; ++dw)
                val[rr][dw] = lin[ic][r0 + rr][col + dw];
        #pragma unroll
        for (int oc = 0; oc < 4; ++oc) {
            const float* wp = w_gw + (size_t)((g*4 + oc)*4 + ic)*9;  // block-uniform -> s_load
            #pragma unroll
            for (int dh = 0; dh < 3; ++dh)
                #pragma unroll
                for (int dw = 0; dw < 3; ++dw) {
                    float w = wp[dh*3 + dw];
                    #pragma unroll
                    for (int r = 0; r < 4; ++r)
                        acc[oc][r] = fmaf(w, val[r + dh][dw], acc[oc][r]);
                }
        }
    }
    unsigned short* dstb = bcdt2 + ((size_t)b*CD + g*4)*NPIX + hbase*64;
    #pragma unroll
    for (int oc = 0; oc < 4; ++oc)
        #pragma unroll
        for (int r = 0; r < 4; ++r)
            dstb[(size_t)oc*NPIX + (r0 + r)*64 + col] = (unsigned short)f2bf(acc[oc][r]);
}

// softmax over N per (b,s); AB = softmax(dt) * BC, bf16 in/out
__global__ __launch_bounds__(256) void k_softmax(const unsigned short* __restrict__ bcdt2,
        unsigned short* __restrict__ AB) {
    int s = blockIdx.x, b = blockIdx.y, t = threadIdx.x;
    const us8* dt = (const us8*)(bcdt2 + ((size_t)b*CD + 64 + s)*NPIX);
    const us8* bc = (const us8*)(bcdt2 + ((size_t)b*CD + s)*NPIX);
    us8* ab = (us8*)(AB + ((size_t)b*SS + s)*NPIX);
    float f[16];
    us8 d0 = dt[t], d1 = dt[256 + t];
    #pragma unroll
    for (int j = 0; j < 8; ++j) { f[j] = bf2f(d0[j]); f[8+j] = bf2f(d1[j]); }
    float mx = -1e30f;
    #pragma unroll
    for (int j = 0; j < 16; ++j) mx = fmaxf(mx, f[j]);
    #pragma unroll
    for (int off = 32; off > 0; off >>= 1) mx = fmaxf(mx, __shfl_down(mx, off, 64));
    __shared__ float buf[8];
    int w = t >> 6;
    if ((t & 63) == 0) buf[w] = mx;
    __syncthreads();
    mx = fmaxf(fmaxf(buf[0], buf[1]), fmaxf(buf[2], buf[3]));
    float sum = 0.f;
    #pragma unroll
    for (int j = 0; j < 16; ++j) { f[j] = __expf(f[j] - mx); sum += f[j]; }
    #pragma unroll
    for (int off = 32; off > 0; off >>= 1) sum += __shfl_down(sum, off, 64);
    if ((t & 63) == 0) buf[4+w] = sum;
    __syncthreads();
    float inv = 1.0f / (buf[4] + buf[5] + buf[6] + buf[7]);
    us8 b0 = bc[t], b1 = bc[256 + t];
    us8 o0, o1;
    #pragma unroll
    for (int j = 0; j < 8; ++j) {
        o0[j] = (unsigned short)f2bf(f[j]   * inv * bf2f(b0[j]));
        o1[j] = (unsigned short)f2bf(f[8+j] * inv * bf2f(b1[j]));
    }
    ab[t] = o0; ab[256 + t] = o1;
}

// BCt[b][n][s] = BC[b][s][n]  (bf16 transpose, LDS tile)
__global__ __launch_bounds__(256) void k_tbc(const unsigned short* __restrict__ bcdt2,
        unsigned short* __restrict__ BCt) {
    int nb = blockIdx.x * 64;
    int b = blockIdx.y;
    __shared__ unsigned short tile[64*65];
    int tt = threadIdx.x;
    #pragma unroll
    for (int k = 0; k < 16; ++k) {
        int idx = k*256 + tt;
        int s = idx >> 6, n = idx & 63;
        tile[s*65 + n] = bcdt2[((size_t)b*CD + s)*NPIX + nb + n];
    }
    __syncthreads();
    #pragma unroll
    for (int k = 0; k < 16; ++k) {
        int idx = k*256 + tt;
        int n = idx >> 6, s = idx & 63;
        BCt[((size_t)b*NPIX + nb + n)*SS + s] = tile[s*65 + n];
    }
}

// h_part[kc][b][c][s] = sum_{n in kc-chunk} x[b][c][n]*AB[b][s][n]  (MFMA)
// block: (ctile64, kc of 8, b); 4 waves split the 512-n chunk; LDS merge.
__global__ __launch_bounds__(256) void k_h(const float* __restrict__ x,
        const unsigned short* __restrict__ AB, float* __restrict__ h_part) {
    int cb = blockIdx.x * 64;
    int kc = blockIdx.y;
    int b = blockIdx.z;
    int tt = threadIdx.x;
    int wid = tt >> 6;
    int l = tt & 63;
    int lane16 = l & 15, q = l >> 4;
    __shared__ __align__(16) float tile[2][64][68];   // [s][c] layout

    f32x4 acc[4][4];
    #pragma unroll
    for (int i = 0; i < 4; ++i)
        #pragma unroll
        for (int j = 0; j < 4; ++j) acc[i][j] = (f32x4){0.f,0.f,0.f,0.f};

    #pragma unroll
    for (int kk = 0; kk < 4; ++kk) {
        int n0 = kc*512 + wid*128 + kk*32;
        bf16x8 afr[4];
        #pragma unroll
        for (int mt = 0; mt < 4; ++mt) {
            const float* ap = x + ((size_t)b*CC + cb + mt*16 + lane16)*NPIX + n0 + q*8;
            float4 u0 = *(const float4*)ap;
            float4 u1 = *(const float4*)(ap + 4);
            afr[mt] = cvt8(u0, u1);
        }
        bf16x8 bfr[4];
        #pragma unroll
        for (int nt = 0; nt < 4; ++nt)
            bfr[nt] = *(const bf16x8*)(AB + ((size_t)b*SS + nt*16 + lane16)*NPIX + n0 + q*8);
        #pragma unroll
        for (int mt = 0; mt < 4; ++mt)
            #pragma unroll
            for (int nt = 0; nt < 4; ++nt)
                acc[mt][nt] = __builtin_amdgcn_mfma_f32_16x16x32_bf16(afr[mt], bfr[nt], acc[mt][nt], 0, 0, 0);
    }

    // cross-wave merge: waves 2,3 -> LDS; 0,1 add; wave 1 -> LDS; 0 adds; 0 writes.
    if (wid >= 2) {
        #pragma unroll
        for (int mt = 0; mt < 4; ++mt)
            #pragma unroll
            for (int nt = 0; nt < 4; ++nt)
                *(float4*)&tile[wid-2][nt*16 + lane16][mt*16 + q*4] = *(float4*)&acc[mt][nt];
    }
    __syncthreads();
    if (wid < 2) {
        #pragma unroll
        for (int mt = 0; mt < 4; ++mt)
            #pragma unroll
            for (int nt = 0; nt < 4; ++nt) {
                float4 v = *(float4*)&tile[wid][nt*16 + lane16][mt*16 + q*4];
                acc[mt][nt][0] += v.x; acc[mt][nt][1] += v.y;
                acc[mt][nt][2] += v.z; acc[mt][nt][3] += v.w;
            }
    }
    __syncthreads();
    if (wid == 1) {
        #pragma unroll
        for (int mt = 0; mt < 4; ++mt)
            #pragma unroll
            for (int nt = 0; nt < 4; ++nt)
                *(float4*)&tile[0][nt*16 + lane16][mt*16 + q*4] = *(float4*)&acc[mt][nt];
    }
    __syncthreads();
    if (wid == 0) {
        float* dst = h_part + ((size_t)kc*BB + b)*CC*SS;
        #pragma unroll
        for (int mt = 0; mt < 4; ++mt)
            #pragma unroll
            for (int nt = 0; nt < 4; ++nt) {
                float4 v = *(float4*)&tile[0][nt*16 + lane16][mt*16 + q*4];
                int s = nt*16 + lane16;
                #pragma unroll
                for (int rr = 0; rr < 4; ++rr) {
                    int c = cb + mt*16 + q*4 + rr;
                    float pv = acc[mt][nt][rr] + ((const float*)&v)[rr];
                    dst[(size_t)c*SS + s] = pv;
                }
            }
    }
}

// h2os[b][o][s] = bf16( sum_c w_outT[c][o] * sum_kc h_part[kc][b][c][s] )
__global__ __launch_bounds__(256) void k_h2(const float* __restrict__ h_part,
        const float* __restrict__ w_outT, unsigned short* __restrict__ h2os) {
    int sbase = blockIdx.x * 8;
    int b = blockIdx.y;
    __shared__ float hl[256*8];
    int t = threadIdx.x;
    #pragma unroll
    for (int k = 0; k < 8; ++k) {
        int idx = k*256 + t;
        int c = idx >> 3, sc = idx & 7;
        size_t base = (size_t)b*CC*SS + (size_t)c*SS + sbase + sc;
        float v = 0.f;
        #pragma unroll
        for (int p = 0; p < 8; ++p)
            v += h_part[base + (size_t)p*BB*CC*SS];
        hl[idx] = v;
    }
    __syncthreads();
    float4 a0 = {0,0,0,0}, a1 = {0,0,0,0};
    #pragma unroll 8
    for (int c = 0; c < 256; ++c) {
        float wv = w_outT[c*256 + t];
        float4 h0 = *(const float4*)(hl + c*8);
        float4 h1 = *(const float4*)(hl + c*8 + 4);
        a0.x = fmaf(wv, h0.x, a0.x); a0.y = fmaf(wv, h0.y, a0.y);
        a0.z = fmaf(wv, h0.z, a0.z); a0.w = fmaf(wv, h0.w, a0.w);
        a1.x = fmaf(wv, h1.x, a1.x); a1.y = fmaf(wv, h1.y, a1.y);
        a1.z = fmaf(wv, h1.z, a1.z); a1.w = fmaf(wv, h1.w, a1.w);
    }
    unsigned short* dst = h2os + ((size_t)b*CC + t)*SS + sbase;
    us8 pk;
    pk[0]=(unsigned short)f2bf(a0.x); pk[1]=(unsigned short)f2bf(a0.y);
    pk[2]=(unsigned short)f2bf(a0.z); pk[3]=(unsigned short)f2bf(a0.w);
    pk[4]=(unsigned short)f2bf(a1.x); pk[5]=(unsigned short)f2bf(a1.y);
    pk[6]=(unsigned short)f2bf(a1.z); pk[7]=(unsigned short)f2bf(a1.w);
    *(us8*)dst = pk;
}

// out[b][o][n] = sum_s h2os[b][o][s]*BCt[b][n][s] + x[b][o][n]  (MFMA, K=64)
__global__ __launch_bounds__(256) void k_out(const float* __restrict__ x,
        const unsigned short* __restrict__ h2os, const unsigned short* __restrict__ BCt,
        float* __restrict__ out) {
    int nb = blockIdx.x * 64;
    int b = blockIdx.y;
    int tt = threadIdx.x;
    int wid = tt >> 6;
    int l = tt & 63;
    int lane16 = l & 15, q = l >> 4;
    int ob = wid * 64;

    f32x4 acc[4][4];
    #pragma unroll
    for (int i = 0; i < 4; ++i)
        #pragma unroll
        for (int j = 0; j < 4; ++j) acc[i][j] = (f32x4){0.f,0.f,0.f,0.f};

    #pragma unroll
    for (int kk = 0; kk < 2; ++kk) {
        int s0 = kk*32;
        bf16x8 afr[4], bfr[4];
        #pragma unroll
        for (int mt = 0; mt < 4; ++mt)
            afr[mt] = *(const bf16x8*)(h2os + ((size_t)b*CC + ob + mt*16 + lane16)*SS + s0 + q*8);
        #pragma unroll
        for (int nt = 0; nt < 4; ++nt)
            bfr[nt] = *(const bf16x8*)(BCt + ((size_t)b*NPIX + nb + nt*16 + lane16)*SS + s0 + q*8);
        #pragma unroll
        for (int mt = 0; mt < 4; ++mt)
            #pragma unroll
            for (int nt = 0; nt < 4; ++nt)
                acc[mt][nt] = __builtin_amdgcn_mfma_f32_16x16x32_bf16(afr[mt], bfr[nt], acc[mt][nt], 0, 0, 0);
    }
    #pragma unroll
    for (int mt = 0; mt < 4; ++mt)
        #pragma unroll
        for (int nt = 0; nt < 4; ++nt) {
            int n = nb + nt*16 + lane16;
            #pragma unroll
            for (int rr = 0; rr < 4; ++rr) {
                int o = ob + mt*16 + q*4 + rr;
                size_t idx = ((size_t)b*CC + o)*NPIX + n;
                out[idx] = acc[mt][nt][rr] + x[idx];
            }
        }
}

extern "C" void kernel_launch(void* const* d_in, const int* in_sizes, int n_in,
                              void* d_out, int out_size, void* d_ws, size_t ws_size,
                              hipStream_t stream) {
    const float* x      = (const float*)d_in[0];
    const float* ln_w   = (const float*)d_in[1];
    const float* ln_b   = (const float*)d_in[2];
    const float* w_bcdt = (const float*)d_in[3];
    const float* w_gw   = (const float*)d_in[4];
    const float* w_out  = (const float*)d_in[5];
    // d_in[6] = A: constant along softmax axis, cancels exactly.
    float* ws  = (float*)d_ws;
    float* out = (float*)d_out;

    unsigned short* W1    = (unsigned short*)(ws + WS_W1);
    float* S1             = ws + WS_S1;
    float* bias           = ws + WS_BIAS;
    float* w_outT         = ws + WS_WOUTT;
    float* bcdt1          = ws + WS_BCDT1;
    unsigned short* bcdt2 = (unsigned short*)(ws + WS_BCDT2);
    unsigned short* AB    = (unsigned short*)(ws + WS_AB);
    unsigned short* BCt   = (unsigned short*)(ws + WS_BCT);
    float* h_part         = ws + WS_HPART;
    unsigned short* h2os  = (unsigned short*)(ws + WS_H2OS);

    k_setup1<<<128, 256, 0, stream>>>(w_bcdt, ln_w, ln_b, W1, S1, bias);
    k_setup2<<<256, 256, 0, stream>>>(w_out, w_outT);
    k_proj<<<dim3(64, 32), 256, 0, stream>>>(x, W1, S1, bias, bcdt1);
    k_gconv<<<dim3(4, 32, 32), 256, 0, stream>>>(bcdt1, w_gw, bcdt2);
    k_softmax<<<dim3(64, 32), 256, 0, stream>>>(bcdt2, AB);
    k_tbc<<<dim3(64, 32), 256, 0, stream>>>(bcdt2, BCt);
    k_h<<<dim3(4, 8, 32), 256, 0, stream>>>(x, AB, h_part);
    k_h2<<<dim3(8, 32), 256, 0, stream>>>(h_part, w_outT, h2os);
    k_out<<<dim3(64, 32), 256, 0, stream>>>(x, h2os, BCt, out);
}